// Round 10
// baseline (1469.150 us; speedup 1.0000x reference)
//
#include <hip/hip_runtime.h>
#include <hip/hip_bf16.h>

// Problem constants: B=64, T=512, I=1024, H=1024 (fp32 in/out).
#define BB_   64
#define TT_   512
#define II_   1024
#define HH_   1024

typedef _Float16 half8  __attribute__((ext_vector_type(8)));
typedef _Float16 half4v __attribute__((ext_vector_type(4)));
typedef float    f32x4  __attribute__((ext_vector_type(4)));

// tanh(x) = 1 - 2/(exp(2x)+1); clamp |x|<=16. ~6 ops vs ocml ~300cy.
__device__ __forceinline__ float fast_tanh(float x) {
    float t = fminf(fmaxf(x, -16.f), 16.f);
    float e = __builtin_amdgcn_exp2f(t * 2.885390082f);   // exp(2t)
    return 1.f - 2.f * __builtin_amdgcn_rcpf(e + 1.f);
}

// ---------------------------------------------------------------------------
// f32 -> f16 convert pass (memory-bound, ~40us for x). Same rounding as the
// old in-staging convert => bit-identical downstream math.
// ---------------------------------------------------------------------------
__global__ __launch_bounds__(256) void cvt_f16(const float4* __restrict__ src,
                                               half4v* __restrict__ dst, int n4) {
    int i = blockIdx.x * blockDim.x + threadIdx.x;
    const int stride = gridDim.x * blockDim.x;
    for (; i < n4; i += stride) {
        const float4 v = src[i];
        half4v h = { (_Float16)v.x, (_Float16)v.y, (_Float16)v.z, (_Float16)v.w };
        dst[i] = h;
    }
}

// ---------------------------------------------------------------------------
// Phase 1 (fast path): f16 GEMM, cvt-free staging.
// Same proven 128x128 / BK=64 / XCD-swizzled structure as r9, but inputs are
// pre-converted f16: staging = 8 b128 loads + 8 b128 LDS stores per thread
// per BK-iter, ZERO cvts (r9: 16 float4 loads + 64 cvts + 16 stores --
// staging-VALU-bound). LDS row stride 72 f16 = 144B (16B-aligned, r9-class
// bank behavior).
// ---------------------------------------------------------------------------
__global__ __launch_bounds__(256) void gemm_xp_f16(const _Float16* __restrict__ xh,
                                                   const _Float16* __restrict__ Wh,
                                                   const float* __restrict__ bih,
                                                   float* __restrict__ out) {
    __shared__ alignas(16) _Float16 As[128 * 72];   // 18KB, [row][64k + 8 pad]
    __shared__ alignas(16) _Float16 Bs[128 * 72];

    const int tid  = threadIdx.x;
    const int xcd  = blockIdx.x & 7;               // same-bm blocks share an XCD
    const int idx  = blockIdx.x >> 3;
    const int bm   = xcd + 8 * (idx >> 3);
    const int bn   = idx & 7;
    const int M0   = bm * 128, N0 = bn * 128;
    const int lane = tid & 63, w = tid >> 6;
    const int wm   = (w & 1) * 64, wn = (w >> 1) * 64;
    const int ro   = lane & 15, q = lane >> 4;
    const int sr   = tid >> 3, sc = tid & 7;       // staging: 32 rows x 8 chunks

    const f32x4 zero4 = {0.f, 0.f, 0.f, 0.f};
    f32x4 acc[4][4];
    #pragma unroll
    for (int i = 0; i < 4; ++i)
        #pragma unroll
        for (int j = 0; j < 4; ++j) acc[i][j] = zero4;

    for (int kk = 0; kk < 16; ++kk) {              // BK=64
        const int k0 = kk * 64;
        #pragma unroll
        for (int ir = 0; ir < 4; ++ir) {
            const int row = ir * 32 + sr;
            const half8 av = *(const half8*)(xh + (size_t)(M0 + row) * II_ + k0 + sc * 8);
            const half8 bv = *(const half8*)(Wh + (size_t)(N0 + row) * II_ + k0 + sc * 8);
            *(half8*)(As + row * 72 + sc * 8) = av;
            *(half8*)(Bs + row * 72 + sc * 8) = bv;
        }
        __syncthreads();

        half8 a[2][4], b[2][4];
        #pragma unroll
        for (int sub = 0; sub < 2; ++sub)
            #pragma unroll
            for (int i = 0; i < 4; ++i) {
                a[sub][i] = *(const half8*)(As + (wm + i * 16 + ro) * 72 + sub * 32 + q * 8);
                b[sub][i] = *(const half8*)(Bs + (wn + i * 16 + ro) * 72 + sub * 32 + q * 8);
            }
        #pragma unroll
        for (int sub = 0; sub < 2; ++sub)
            #pragma unroll
            for (int i = 0; i < 4; ++i)
                #pragma unroll
                for (int j = 0; j < 4; ++j)
                    acc[i][j] = __builtin_amdgcn_mfma_f32_16x16x32_f16(a[sub][i], b[sub][j], acc[i][j], 0, 0, 0);
        __syncthreads();
    }

    #pragma unroll
    for (int j = 0; j < 4; ++j) {
        const int col = N0 + wn + j * 16 + ro;
        const float bias = bih[col];
        #pragma unroll
        for (int i = 0; i < 4; ++i) {
            #pragma unroll
            for (int r = 0; r < 4; ++r) {
                const int rowg = M0 + wm + i * 16 + q * 4 + r;
                out[(size_t)rowg * HH_ + col] = acc[i][j][r] + bias;
            }
        }
    }
}

// ---------------------------------------------------------------------------
// Phase 1 (fallback, ws too small): r9 gemm verbatim.
// ---------------------------------------------------------------------------
__global__ __launch_bounds__(256) void gemm_xp(const float* __restrict__ x,
                                               const float* __restrict__ Wih,
                                               const float* __restrict__ bih,
                                               float* __restrict__ out) {
    __shared__ alignas(16) _Float16 As[2][128 * 40];
    __shared__ alignas(16) _Float16 Bs[2][128 * 40];

    const int tid  = threadIdx.x;
    const int xcd  = blockIdx.x & 7;
    const int idx  = blockIdx.x >> 3;
    const int bm   = xcd + 8 * (idx >> 3);
    const int bn   = idx & 7;
    const int M0   = bm * 128, N0 = bn * 128;
    const int lane = tid & 63, w = tid >> 6;
    const int wm   = (w & 1) * 64, wn = (w >> 1) * 64;
    const int ro   = lane & 15, q = lane >> 4;
    const int sr   = tid >> 3, sc = tid & 7;

    const f32x4 zero4 = {0.f, 0.f, 0.f, 0.f};
    f32x4 acc[4][4];
    #pragma unroll
    for (int i = 0; i < 4; ++i)
        #pragma unroll
        for (int j = 0; j < 4; ++j) acc[i][j] = zero4;

    for (int kk = 0; kk < 16; ++kk) {
        #pragma unroll
        for (int sub = 0; sub < 2; ++sub) {
            const int k0 = kk * 64 + sub * 32;
            #pragma unroll
            for (int ir = 0; ir < 4; ++ir) {
                const int row = ir * 32 + sr;
                const float4 av = *(const float4*)(x   + (size_t)(M0 + row) * II_ + k0 + sc * 4);
                const float4 bv = *(const float4*)(Wih + (size_t)(N0 + row) * II_ + k0 + sc * 4);
                half4v ah = { (_Float16)av.x, (_Float16)av.y, (_Float16)av.z, (_Float16)av.w };
                half4v bh = { (_Float16)bv.x, (_Float16)bv.y, (_Float16)bv.z, (_Float16)bv.w };
                *(half4v*)(As[sub] + row * 40 + sc * 4) = ah;
                *(half4v*)(Bs[sub] + row * 40 + sc * 4) = bh;
            }
        }
        __syncthreads();

        half8 a[2][4], b[2][4];
        #pragma unroll
        for (int sub = 0; sub < 2; ++sub)
            #pragma unroll
            for (int i = 0; i < 4; ++i) {
                a[sub][i] = *(const half8*)(As[sub] + (wm + i * 16 + ro) * 40 + q * 8);
                b[sub][i] = *(const half8*)(Bs[sub] + (wn + i * 16 + ro) * 40 + q * 8);
            }
        #pragma unroll
        for (int sub = 0; sub < 2; ++sub)
            #pragma unroll
            for (int i = 0; i < 4; ++i)
                #pragma unroll
                for (int j = 0; j < 4; ++j)
                    acc[i][j] = __builtin_amdgcn_mfma_f32_16x16x32_f16(a[sub][i], b[sub][j], acc[i][j], 0, 0, 0);
        __syncthreads();
    }

    #pragma unroll
    for (int j = 0; j < 4; ++j) {
        const int col = N0 + wn + j * 16 + ro;
        const float bias = bih[col];
        #pragma unroll
        for (int i = 0; i < 4; ++i) {
            #pragma unroll
            for (int r = 0; r < 4; ++r) {
                const int rowg = M0 + wm + i * 16 + q * 4 + r;
                out[(size_t)rowg * HH_ + col] = acc[i][j][r] + bias;
            }
        }
    }
}

// ---------------------------------------------------------------------------
// Phase 2: persistent recurrence -- r9 structure (best: 1138us) with a
// 2-deep SOFTWARE-PIPELINED poll: always keep one poll round in flight while
// checking the previous, halving post->discovery latency (~600 -> ~300cy).
// Same loads, same tagged-word agent-scope protocol (passed r1/r3/r6/r9);
// per-lane divergent exit + sel-merge. Everything else r9-verbatim.
// ---------------------------------------------------------------------------
__global__ __launch_bounds__(256, 1) void rnn_steps(const float* __restrict__ Whh,
                                                    const float* __restrict__ bhh,
                                                    const float* __restrict__ h0,
                                                    float* __restrict__ out,
                                                    unsigned* __restrict__ comm) {
    __shared__ alignas(16) _Float16 hbuf[2][5][1032];

    const int tid  = threadIdx.x;
    const int lane = tid & 63;
    const int w    = tid >> 6;             // wave id: stages batch w, owns 16 cols
    const int g    = blockIdx.x >> 4;      // group 0..15
    const int wg   = blockIdx.x & 15;      // wg within group
    const int b0   = g * 4;
    const int j0   = wg * 64;
    const int ro   = lane & 15, q = lane >> 4;
    const int arow = (ro < 4) ? ro : 4;    // A rows >=4 read the shared zero row
    const int bat  = lane >> 4;
    const int colw = j0 + w * 16 + (lane & 15);

    // Preload W_hh B-fragments (full K): 128 VGPRs.
    half8 wf[4][8];
    {
        const float* wrow = Whh + (size_t)(j0 + w * 16 + ro) * HH_;
        #pragma unroll
        for (int kq = 0; kq < 4; ++kq) {
            #pragma unroll
            for (int ks = 0; ks < 8; ++ks) {
                const int kc = kq * 256 + ks * 32 + q * 8;
                const float4 w0 = *(const float4*)(wrow + kc);
                const float4 w1 = *(const float4*)(wrow + kc + 4);
                half8 hv;
                hv[0] = (_Float16)w0.x; hv[1] = (_Float16)w0.y;
                hv[2] = (_Float16)w0.z; hv[3] = (_Float16)w0.w;
                hv[4] = (_Float16)w1.x; hv[5] = (_Float16)w1.y;
                hv[6] = (_Float16)w1.z; hv[7] = (_Float16)w1.w;
                wf[kq][ks] = hv;
            }
        }
    }
    const float bhh_r = bhh[colw];

    for (int i = tid; i < 1032; i += 256) {
        hbuf[0][4][i] = (_Float16)0.f;
        hbuf[1][4][i] = (_Float16)0.f;
    }

    const f32x4 zero4 = {0.f, 0.f, 0.f, 0.f};

    #define TAGMSK_ 0xFFFF0000FFFF0000ull
    #define TAGOK_(v) ((((v) ^ pat) & TAGMSK_) == 0)
    #define AL_(p) __hip_atomic_load((p), __ATOMIC_RELAXED, __HIP_MEMORY_SCOPE_AGENT)

    for (int s = 0; s < TT_; ++s) {
        const int slot = s & 1;

        // xp prefetch: issued first so its latency hides under the poll.
        const float xpv = out[((size_t)(b0 + bat) * TT_ + s) * HH_ + colw];

        unsigned* dstw = (unsigned*)(&hbuf[slot][w][0]);
        if (s == 0) {
            const float2* hrow = (const float2*)(h0 + (size_t)(b0 + w) * HH_);
            #pragma unroll
            for (int c = 0; c < 8; ++c) {
                const float2 hv = hrow[c * 64 + lane];
                union { _Float16 h[2]; unsigned u; } pk;
                pk.h[0] = (_Float16)hv.x; pk.h[1] = (_Float16)hv.y;
                dstw[c * 64 + lane] = pk.u;
            }
        } else {
            const unsigned long long pat =
                ((unsigned long long)(unsigned)s << 48) |
                ((unsigned long long)(unsigned)s << 16);
            const unsigned long long* sp = (const unsigned long long*)
                (comm + (size_t)slot * (BB_ * HH_) + (size_t)(b0 + w) * HH_);

            unsigned long long a0, a1, a2, a3, a4, a5, a6, a7;
            unsigned long long c0, c1, c2, c3, c4, c5, c6, c7;
            bool sel;
            // prime round A
            a0 = AL_(sp + 0 * 64 + lane); a1 = AL_(sp + 1 * 64 + lane);
            a2 = AL_(sp + 2 * 64 + lane); a3 = AL_(sp + 3 * 64 + lane);
            a4 = AL_(sp + 4 * 64 + lane); a5 = AL_(sp + 5 * 64 + lane);
            a6 = AL_(sp + 6 * 64 + lane); a7 = AL_(sp + 7 * 64 + lane);
            for (;;) {
                // issue round C while checking A (A's wait leaves C in flight)
                c0 = AL_(sp + 0 * 64 + lane); c1 = AL_(sp + 1 * 64 + lane);
                c2 = AL_(sp + 2 * 64 + lane); c3 = AL_(sp + 3 * 64 + lane);
                c4 = AL_(sp + 4 * 64 + lane); c5 = AL_(sp + 5 * 64 + lane);
                c6 = AL_(sp + 6 * 64 + lane); c7 = AL_(sp + 7 * 64 + lane);
                {
                    bool o = true;
                    o &= TAGOK_(a0); o &= TAGOK_(a1); o &= TAGOK_(a2); o &= TAGOK_(a3);
                    o &= TAGOK_(a4); o &= TAGOK_(a5); o &= TAGOK_(a6); o &= TAGOK_(a7);
                    if (o) { sel = true; break; }
                }
                a0 = AL_(sp + 0 * 64 + lane); a1 = AL_(sp + 1 * 64 + lane);
                a2 = AL_(sp + 2 * 64 + lane); a3 = AL_(sp + 3 * 64 + lane);
                a4 = AL_(sp + 4 * 64 + lane); a5 = AL_(sp + 5 * 64 + lane);
                a6 = AL_(sp + 6 * 64 + lane); a7 = AL_(sp + 7 * 64 + lane);
                {
                    bool o = true;
                    o &= TAGOK_(c0); o &= TAGOK_(c1); o &= TAGOK_(c2); o &= TAGOK_(c3);
                    o &= TAGOK_(c4); o &= TAGOK_(c5); o &= TAGOK_(c6); o &= TAGOK_(c7);
                    if (o) { sel = false; break; }
                }
            }
            const unsigned long long v0 = sel ? a0 : c0;
            const unsigned long long v1 = sel ? a1 : c1;
            const unsigned long long v2 = sel ? a2 : c2;
            const unsigned long long v3 = sel ? a3 : c3;
            const unsigned long long v4 = sel ? a4 : c4;
            const unsigned long long v5 = sel ? a5 : c5;
            const unsigned long long v6 = sel ? a6 : c6;
            const unsigned long long v7 = sel ? a7 : c7;
            #define PACK_(x) ((unsigned)((x) & 0xffffull) | (((unsigned)((x) >> 32)) << 16))
            dstw[0 * 64 + lane] = PACK_(v0);
            dstw[1 * 64 + lane] = PACK_(v1);
            dstw[2 * 64 + lane] = PACK_(v2);
            dstw[3 * 64 + lane] = PACK_(v3);
            dstw[4 * 64 + lane] = PACK_(v4);
            dstw[5 * 64 + lane] = PACK_(v5);
            dstw[6 * 64 + lane] = PACK_(v6);
            dstw[7 * 64 + lane] = PACK_(v7);
            #undef PACK_
        }
        __syncthreads();   // the only barrier per step (LDS double-buffered)

        // ---- MFMA: this wave's 16 cols x full K=1024, 4 independent chains
        f32x4 acc[4] = {zero4, zero4, zero4, zero4};
        const _Float16* abase = &hbuf[slot][0][0] + (size_t)arow * 1032;
        #pragma unroll
        for (int kq = 0; kq < 4; ++kq) {
            #pragma unroll
            for (int ks = 0; ks < 8; ++ks) {
                const half8 a = *(const half8*)(abase + kq * 256 + ks * 32 + q * 8);
                acc[kq] = __builtin_amdgcn_mfma_f32_16x16x32_f16(a, wf[kq][ks], acc[kq], 0, 0, 0);
            }
        }

        // ---- epilogue, all 64 lanes ----
        const f32x4 sum = acc[0] + acc[1] + acc[2] + acc[3];
        const float t0 = __shfl(sum[0], lane & 15);
        const float t1 = __shfl(sum[1], lane & 15);
        const float t2 = __shfl(sum[2], lane & 15);
        const float t3 = __shfl(sum[3], lane & 15);
        const float val = (bat == 0) ? t0 : (bat == 1) ? t1 : (bat == 2) ? t2 : t3;

        const float hnew = fast_tanh(xpv + bhh_r + val);

        // tagged comm word FIRST (inter-WG critical path), out store after.
        union { _Float16 h; unsigned short us; } cv; cv.h = (_Float16)hnew;
        const unsigned word = ((unsigned)(s + 1) << 16) | (unsigned)cv.us;
        __hip_atomic_store(comm + (size_t)((s + 1) & 1) * (BB_ * HH_)
                                + (size_t)(b0 + bat) * HH_ + colw,
                           word, __ATOMIC_RELAXED, __HIP_MEMORY_SCOPE_AGENT);

        out[((size_t)(b0 + bat) * TT_ + s) * HH_ + colw] = hnew;
    }
    #undef TAGOK_
    #undef TAGMSK_
    #undef AL_
}

// ---------------------------------------------------------------------------
extern "C" void kernel_launch(void* const* d_in, const int* in_sizes, int n_in,
                              void* d_out, int out_size, void* d_ws, size_t ws_size,
                              hipStream_t stream) {
    (void)in_sizes; (void)n_in; (void)out_size;

    const float* x   = (const float*)d_in[0];
    const float* h0  = (const float*)d_in[1];
    const float* Wih = (const float*)d_in[2];
    const float* bih = (const float*)d_in[3];
    const float* Whh = (const float*)d_in[4];
    const float* bhh = (const float*)d_in[5];
    float* out = (float*)d_out;

    // ws layout: comm (512KB, r1-proven offsets) | Wih_f16 (2MB) | x_f16 (64MB)
    const size_t COMMB = 2 * (size_t)(BB_ * HH_) * sizeof(unsigned);
    const size_t WFB   = (size_t)HH_ * II_ * sizeof(_Float16);
    const size_t XFB   = (size_t)BB_ * TT_ * II_ * sizeof(_Float16);
    unsigned* comm = (unsigned*)d_ws;

    if (ws_size >= COMMB + WFB + XFB) {
        _Float16* Wh = (_Float16*)((char*)d_ws + COMMB);
        _Float16* xh = (_Float16*)((char*)d_ws + COMMB + WFB);
        cvt_f16<<<512, 256, 0, stream>>>((const float4*)Wih, (half4v*)Wh,
                                         HH_ * II_ / 4);
        cvt_f16<<<2048, 256, 0, stream>>>((const float4*)x, (half4v*)xh,
                                          BB_ * TT_ * II_ / 4);
        gemm_xp_f16<<<2048, 256, 0, stream>>>(xh, Wh, bih, out);
    } else {
        gemm_xp<<<2048, 256, 0, stream>>>(x, Wih, bih, out);
    }
    rnn_steps<<<256, 256, 0, stream>>>(Whh, bhh, h0, out, comm);
}

// Round 11
// 1421.028 us; speedup vs baseline: 1.0339x; 1.0339x over previous
//
#include <hip/hip_runtime.h>
#include <hip/hip_bf16.h>

// Problem constants: B=64, T=512, I=1024, H=1024 (fp32 in/out).
#define BB_   64
#define TT_   512
#define II_   1024
#define HH_   1024

typedef _Float16 half8  __attribute__((ext_vector_type(8)));
typedef _Float16 half4v __attribute__((ext_vector_type(4)));
typedef float    f32x4  __attribute__((ext_vector_type(4)));

// tanh(x) = 1 - 2/(exp(2x)+1); clamp |x|<=16. ~6 ops vs ocml ~300cy.
__device__ __forceinline__ float fast_tanh(float x) {
    float t = fminf(fmaxf(x, -16.f), 16.f);
    float e = __builtin_amdgcn_exp2f(t * 2.885390082f);   // exp(2t)
    return 1.f - 2.f * __builtin_amdgcn_rcpf(e + 1.f);
}

// ---------------------------------------------------------------------------
// f32 -> f16 convert pass (memory-bound). Same rounding as the old
// in-staging convert => bit-identical downstream math. (r10-proven)
// ---------------------------------------------------------------------------
__global__ __launch_bounds__(256) void cvt_f16(const float4* __restrict__ src,
                                               half4v* __restrict__ dst, int n4) {
    int i = blockIdx.x * blockDim.x + threadIdx.x;
    const int stride = gridDim.x * blockDim.x;
    for (; i < n4; i += stride) {
        const float4 v = src[i];
        half4v h = { (_Float16)v.x, (_Float16)v.y, (_Float16)v.z, (_Float16)v.w };
        dst[i] = h;
    }
}

// ---------------------------------------------------------------------------
// Phase 1 (fast path): f16 GEMM, cvt-free staging. (r10-proven: phase-1
// total 323 -> 277us vs r9.) 128x128 / BK=64 / XCD-swizzled; staging = 8
// b128 loads + 8 b128 LDS stores per thread per BK-iter, zero cvts.
// ---------------------------------------------------------------------------
__global__ __launch_bounds__(256) void gemm_xp_f16(const _Float16* __restrict__ xh,
                                                   const _Float16* __restrict__ Wh,
                                                   const float* __restrict__ bih,
                                                   float* __restrict__ out) {
    __shared__ alignas(16) _Float16 As[128 * 72];   // 18KB, [row][64k + 8 pad]
    __shared__ alignas(16) _Float16 Bs[128 * 72];

    const int tid  = threadIdx.x;
    const int xcd  = blockIdx.x & 7;               // same-bm blocks share an XCD
    const int idx  = blockIdx.x >> 3;
    const int bm   = xcd + 8 * (idx >> 3);
    const int bn   = idx & 7;
    const int M0   = bm * 128, N0 = bn * 128;
    const int lane = tid & 63, w = tid >> 6;
    const int wm   = (w & 1) * 64, wn = (w >> 1) * 64;
    const int ro   = lane & 15, q = lane >> 4;
    const int sr   = tid >> 3, sc = tid & 7;       // staging: 32 rows x 8 chunks

    const f32x4 zero4 = {0.f, 0.f, 0.f, 0.f};
    f32x4 acc[4][4];
    #pragma unroll
    for (int i = 0; i < 4; ++i)
        #pragma unroll
        for (int j = 0; j < 4; ++j) acc[i][j] = zero4;

    for (int kk = 0; kk < 16; ++kk) {              // BK=64
        const int k0 = kk * 64;
        #pragma unroll
        for (int ir = 0; ir < 4; ++ir) {
            const int row = ir * 32 + sr;
            const half8 av = *(const half8*)(xh + (size_t)(M0 + row) * II_ + k0 + sc * 8);
            const half8 bv = *(const half8*)(Wh + (size_t)(N0 + row) * II_ + k0 + sc * 8);
            *(half8*)(As + row * 72 + sc * 8) = av;
            *(half8*)(Bs + row * 72 + sc * 8) = bv;
        }
        __syncthreads();

        half8 a[2][4], b[2][4];
        #pragma unroll
        for (int sub = 0; sub < 2; ++sub)
            #pragma unroll
            for (int i = 0; i < 4; ++i) {
                a[sub][i] = *(const half8*)(As + (wm + i * 16 + ro) * 72 + sub * 32 + q * 8);
                b[sub][i] = *(const half8*)(Bs + (wn + i * 16 + ro) * 72 + sub * 32 + q * 8);
            }
        #pragma unroll
        for (int sub = 0; sub < 2; ++sub)
            #pragma unroll
            for (int i = 0; i < 4; ++i)
                #pragma unroll
                for (int j = 0; j < 4; ++j)
                    acc[i][j] = __builtin_amdgcn_mfma_f32_16x16x32_f16(a[sub][i], b[sub][j], acc[i][j], 0, 0, 0);
        __syncthreads();
    }

    #pragma unroll
    for (int j = 0; j < 4; ++j) {
        const int col = N0 + wn + j * 16 + ro;
        const float bias = bih[col];
        #pragma unroll
        for (int i = 0; i < 4; ++i) {
            #pragma unroll
            for (int r = 0; r < 4; ++r) {
                const int rowg = M0 + wm + i * 16 + q * 4 + r;
                out[(size_t)rowg * HH_ + col] = acc[i][j][r] + bias;
            }
        }
    }
}

// ---------------------------------------------------------------------------
// Phase 1 (fallback, ws too small): r9 gemm verbatim.
// ---------------------------------------------------------------------------
__global__ __launch_bounds__(256) void gemm_xp(const float* __restrict__ x,
                                               const float* __restrict__ Wih,
                                               const float* __restrict__ bih,
                                               float* __restrict__ out) {
    __shared__ alignas(16) _Float16 As[2][128 * 40];
    __shared__ alignas(16) _Float16 Bs[2][128 * 40];

    const int tid  = threadIdx.x;
    const int xcd  = blockIdx.x & 7;
    const int idx  = blockIdx.x >> 3;
    const int bm   = xcd + 8 * (idx >> 3);
    const int bn   = idx & 7;
    const int M0   = bm * 128, N0 = bn * 128;
    const int lane = tid & 63, w = tid >> 6;
    const int wm   = (w & 1) * 64, wn = (w >> 1) * 64;
    const int ro   = lane & 15, q = lane >> 4;
    const int sr   = tid >> 3, sc = tid & 7;

    const f32x4 zero4 = {0.f, 0.f, 0.f, 0.f};
    f32x4 acc[4][4];
    #pragma unroll
    for (int i = 0; i < 4; ++i)
        #pragma unroll
        for (int j = 0; j < 4; ++j) acc[i][j] = zero4;

    for (int kk = 0; kk < 16; ++kk) {
        #pragma unroll
        for (int sub = 0; sub < 2; ++sub) {
            const int k0 = kk * 64 + sub * 32;
            #pragma unroll
            for (int ir = 0; ir < 4; ++ir) {
                const int row = ir * 32 + sr;
                const float4 av = *(const float4*)(x   + (size_t)(M0 + row) * II_ + k0 + sc * 4);
                const float4 bv = *(const float4*)(Wih + (size_t)(N0 + row) * II_ + k0 + sc * 4);
                half4v ah = { (_Float16)av.x, (_Float16)av.y, (_Float16)av.z, (_Float16)av.w };
                half4v bh = { (_Float16)bv.x, (_Float16)bv.y, (_Float16)bv.z, (_Float16)bv.w };
                *(half4v*)(As[sub] + row * 40 + sc * 4) = ah;
                *(half4v*)(Bs[sub] + row * 40 + sc * 4) = bh;
            }
        }
        __syncthreads();

        half8 a[2][4], b[2][4];
        #pragma unroll
        for (int sub = 0; sub < 2; ++sub)
            #pragma unroll
            for (int i = 0; i < 4; ++i) {
                a[sub][i] = *(const half8*)(As[sub] + (wm + i * 16 + ro) * 40 + q * 8);
                b[sub][i] = *(const half8*)(Bs[sub] + (wn + i * 16 + ro) * 40 + q * 8);
            }
        #pragma unroll
        for (int sub = 0; sub < 2; ++sub)
            #pragma unroll
            for (int i = 0; i < 4; ++i)
                #pragma unroll
                for (int j = 0; j < 4; ++j)
                    acc[i][j] = __builtin_amdgcn_mfma_f32_16x16x32_f16(a[sub][i], b[sub][j], acc[i][j], 0, 0, 0);
        __syncthreads();
    }

    #pragma unroll
    for (int j = 0; j < 4; ++j) {
        const int col = N0 + wn + j * 16 + ro;
        const float bias = bih[col];
        #pragma unroll
        for (int i = 0; i < 4; ++i) {
            #pragma unroll
            for (int r = 0; r < 4; ++r) {
                const int rowg = M0 + wm + i * 16 + q * 4 + r;
                out[(size_t)rowg * HH_ + col] = acc[i][j][r] + bias;
            }
        }
    }
}

// ---------------------------------------------------------------------------
// Phase 2: persistent recurrence -- r9 VERBATIM (best measured: 1138us).
// Simple single-round poll + 3-op XOR tag check. The pipelined poll (r10),
// sc0 store (r2/r4), sc0 poll (r3), degree-8 (r7), fat-WG (r5), fusion (r8)
// are all empirically retired -- every addition to the poll loop or the
// step's serial chain costs ~1.2x its cycle count in step period.
// ---------------------------------------------------------------------------
__global__ __launch_bounds__(256, 1) void rnn_steps(const float* __restrict__ Whh,
                                                    const float* __restrict__ bhh,
                                                    const float* __restrict__ h0,
                                                    float* __restrict__ out,
                                                    unsigned* __restrict__ comm) {
    // [slot][row][col]: rows 0..3 = batches (f16 h), row 4 = zeros (pads MFMA
    // A rows 4..15). Row stride 1032 f16 = 2064 B.
    __shared__ alignas(16) _Float16 hbuf[2][5][1032];

    const int tid  = threadIdx.x;
    const int lane = tid & 63;
    const int w    = tid >> 6;             // wave id: stages batch w, owns 16 cols
    const int g    = blockIdx.x >> 4;      // group 0..15
    const int wg   = blockIdx.x & 15;      // wg within group
    const int b0   = g * 4;
    const int j0   = wg * 64;
    const int ro   = lane & 15, q = lane >> 4;
    const int arow = (ro < 4) ? ro : 4;    // A rows >=4 read the shared zero row
    const int bat  = lane >> 4;            // epilogue: this lane's batch 0..3
    const int colw = j0 + w * 16 + (lane & 15);  // epilogue: this lane's column

    // Preload W_hh B-fragments (full K): wf[kq][ks][e] = Whh[n][k],
    // n = j0 + w*16 + ro, k = kq*256 + ks*32 + q*8 + e. 128 VGPRs.
    half8 wf[4][8];
    {
        const float* wrow = Whh + (size_t)(j0 + w * 16 + ro) * HH_;
        #pragma unroll
        for (int kq = 0; kq < 4; ++kq) {
            #pragma unroll
            for (int ks = 0; ks < 8; ++ks) {
                const int kc = kq * 256 + ks * 32 + q * 8;
                const float4 w0 = *(const float4*)(wrow + kc);
                const float4 w1 = *(const float4*)(wrow + kc + 4);
                half8 hv;
                hv[0] = (_Float16)w0.x; hv[1] = (_Float16)w0.y;
                hv[2] = (_Float16)w0.z; hv[3] = (_Float16)w0.w;
                hv[4] = (_Float16)w1.x; hv[5] = (_Float16)w1.y;
                hv[6] = (_Float16)w1.z; hv[7] = (_Float16)w1.w;
                wf[kq][ks] = hv;
            }
        }
    }
    const float bhh_r = bhh[colw];

    // zero row 4 of both LDS slots
    for (int i = tid; i < 1032; i += 256) {
        hbuf[0][4][i] = (_Float16)0.f;
        hbuf[1][4][i] = (_Float16)0.f;
    }

    const f32x4 zero4 = {0.f, 0.f, 0.f, 0.f};

    // tag check: word = {tag:16|payload:16} x2 per u64. 3 ops/u64.
    #define TAGMSK_ 0xFFFF0000FFFF0000ull
    #define TAGOK_(v) ((((v) ^ pat) & TAGMSK_) == 0)

    for (int s = 0; s < TT_; ++s) {
        const int slot = s & 1;

        // xp prefetch: one value per lane (batch bat, col colw); issued first
        // so its latency hides under the poll.
        const float xpv = out[((size_t)(b0 + bat) * TT_ + s) * HH_ + colw];

        // ---- stage h_s into hbuf[slot][w][:] as packed f16 pairs ----
        unsigned* dstw = (unsigned*)(&hbuf[slot][w][0]);
        if (s == 0) {
            const float2* hrow = (const float2*)(h0 + (size_t)(b0 + w) * HH_);
            #pragma unroll
            for (int c = 0; c < 8; ++c) {
                const float2 hv = hrow[c * 64 + lane];
                union { _Float16 h[2]; unsigned u; } pk;
                pk.h[0] = (_Float16)hv.x; pk.h[1] = (_Float16)hv.y;
                dstw[c * 64 + lane] = pk.u;
            }
        } else {
            // poll own batch row (8 u64 per lane = 4KB per wave); each 32-bit
            // half carries its own tag => tearing harmless.
            const unsigned long long pat =
                ((unsigned long long)(unsigned)s << 48) |
                ((unsigned long long)(unsigned)s << 16);
            const unsigned long long* sp = (const unsigned long long*)
                (comm + (size_t)slot * (BB_ * HH_) + (size_t)(b0 + w) * HH_);
            unsigned long long v0, v1, v2, v3, v4, v5, v6, v7;
            bool ok = false;
            while (!ok) {
                v0 = __hip_atomic_load(sp + 0 * 64 + lane, __ATOMIC_RELAXED, __HIP_MEMORY_SCOPE_AGENT);
                v1 = __hip_atomic_load(sp + 1 * 64 + lane, __ATOMIC_RELAXED, __HIP_MEMORY_SCOPE_AGENT);
                v2 = __hip_atomic_load(sp + 2 * 64 + lane, __ATOMIC_RELAXED, __HIP_MEMORY_SCOPE_AGENT);
                v3 = __hip_atomic_load(sp + 3 * 64 + lane, __ATOMIC_RELAXED, __HIP_MEMORY_SCOPE_AGENT);
                v4 = __hip_atomic_load(sp + 4 * 64 + lane, __ATOMIC_RELAXED, __HIP_MEMORY_SCOPE_AGENT);
                v5 = __hip_atomic_load(sp + 5 * 64 + lane, __ATOMIC_RELAXED, __HIP_MEMORY_SCOPE_AGENT);
                v6 = __hip_atomic_load(sp + 6 * 64 + lane, __ATOMIC_RELAXED, __HIP_MEMORY_SCOPE_AGENT);
                v7 = __hip_atomic_load(sp + 7 * 64 + lane, __ATOMIC_RELAXED, __HIP_MEMORY_SCOPE_AGENT);
                bool o = true;
                o &= TAGOK_(v0); o &= TAGOK_(v1); o &= TAGOK_(v2); o &= TAGOK_(v3);
                o &= TAGOK_(v4); o &= TAGOK_(v5); o &= TAGOK_(v6); o &= TAGOK_(v7);
                ok = o;
            }
            // pack two f16 halves -> one b32 LDS write (stride-4B, conflict-free)
            #define PACK_(x) ((unsigned)((x) & 0xffffull) | (((unsigned)((x) >> 32)) << 16))
            dstw[0 * 64 + lane] = PACK_(v0);
            dstw[1 * 64 + lane] = PACK_(v1);
            dstw[2 * 64 + lane] = PACK_(v2);
            dstw[3 * 64 + lane] = PACK_(v3);
            dstw[4 * 64 + lane] = PACK_(v4);
            dstw[5 * 64 + lane] = PACK_(v5);
            dstw[6 * 64 + lane] = PACK_(v6);
            dstw[7 * 64 + lane] = PACK_(v7);
            #undef PACK_
        }
        __syncthreads();   // the only barrier per step (LDS double-buffered)

        // ---- MFMA: this wave's 16 cols x full K=1024, 4 independent chains
        f32x4 acc[4] = {zero4, zero4, zero4, zero4};
        const _Float16* abase = &hbuf[slot][0][0] + (size_t)arow * 1032;
        #pragma unroll
        for (int kq = 0; kq < 4; ++kq) {
            #pragma unroll
            for (int ks = 0; ks < 8; ++ks) {
                const half8 a = *(const half8*)(abase + kq * 256 + ks * 32 + q * 8);
                acc[kq] = __builtin_amdgcn_mfma_f32_16x16x32_f16(a, wf[kq][ks], acc[kq], 0, 0, 0);
            }
        }

        // ---- epilogue, all 64 lanes: redistribute D (row = batch on q==0
        // lanes, col = lane&15) so each lane owns one (batch, col) value.
        const f32x4 sum = acc[0] + acc[1] + acc[2] + acc[3];
        const float t0 = __shfl(sum[0], lane & 15);
        const float t1 = __shfl(sum[1], lane & 15);
        const float t2 = __shfl(sum[2], lane & 15);
        const float t3 = __shfl(sum[3], lane & 15);
        const float val = (bat == 0) ? t0 : (bat == 1) ? t1 : (bat == 2) ? t2 : t3;

        const float hnew = fast_tanh(xpv + bhh_r + val);

        // tagged comm word FIRST (inter-WG critical path), out store after.
        union { _Float16 h; unsigned short us; } cv; cv.h = (_Float16)hnew;
        const unsigned word = ((unsigned)(s + 1) << 16) | (unsigned)cv.us;
        __hip_atomic_store(comm + (size_t)((s + 1) & 1) * (BB_ * HH_)
                                + (size_t)(b0 + bat) * HH_ + colw,
                           word, __ATOMIC_RELAXED, __HIP_MEMORY_SCOPE_AGENT);

        out[((size_t)(b0 + bat) * TT_ + s) * HH_ + colw] = hnew;
        // no trailing barrier: next step stages into hbuf[slot^1]; reuse at
        // distance 2 is ordered by the step s+1 __syncthreads.
    }
    #undef TAGOK_
    #undef TAGMSK_
}

// ---------------------------------------------------------------------------
extern "C" void kernel_launch(void* const* d_in, const int* in_sizes, int n_in,
                              void* d_out, int out_size, void* d_ws, size_t ws_size,
                              hipStream_t stream) {
    (void)in_sizes; (void)n_in; (void)out_size;

    const float* x   = (const float*)d_in[0];
    const float* h0  = (const float*)d_in[1];
    const float* Wih = (const float*)d_in[2];
    const float* bih = (const float*)d_in[3];
    const float* Whh = (const float*)d_in[4];
    const float* bhh = (const float*)d_in[5];
    float* out = (float*)d_out;

    // ws layout: comm (512KB, r1-proven offsets) | Wih_f16 (2MB) | x_f16 (64MB)
    const size_t COMMB = 2 * (size_t)(BB_ * HH_) * sizeof(unsigned);
    const size_t WFB   = (size_t)HH_ * II_ * sizeof(_Float16);
    const size_t XFB   = (size_t)BB_ * TT_ * II_ * sizeof(_Float16);
    unsigned* comm = (unsigned*)d_ws;

    if (ws_size >= COMMB + WFB + XFB) {
        _Float16* Wh = (_Float16*)((char*)d_ws + COMMB);
        _Float16* xh = (_Float16*)((char*)d_ws + COMMB + WFB);
        cvt_f16<<<512, 256, 0, stream>>>((const float4*)Wih, (half4v*)Wh,
                                         HH_ * II_ / 4);
        cvt_f16<<<2048, 256, 0, stream>>>((const float4*)x, (half4v*)xh,
                                          BB_ * TT_ * II_ / 4);
        gemm_xp_f16<<<2048, 256, 0, stream>>>(xh, Wh, bih, out);
    } else {
        gemm_xp<<<2048, 256, 0, stream>>>(x, Wih, bih, out);
    }
    rnn_steps<<<256, 256, 0, stream>>>(Whh, bhh, h0, out, comm);
}

// Round 12
// 1415.777 us; speedup vs baseline: 1.0377x; 1.0037x over previous
//
#include <hip/hip_runtime.h>
#include <hip/hip_bf16.h>

// Problem constants: B=64, T=512, I=1024, H=1024 (fp32 in/out).
#define BB_   64
#define TT_   512
#define II_   1024
#define HH_   1024

typedef _Float16 half8  __attribute__((ext_vector_type(8)));
typedef _Float16 half4v __attribute__((ext_vector_type(4)));
typedef float    f32x4  __attribute__((ext_vector_type(4)));

// tanh(x) = 1 - 2/(exp(2x)+1); clamp |x|<=16. ~6 ops vs ocml ~300cy.
__device__ __forceinline__ float fast_tanh(float x) {
    float t = fminf(fmaxf(x, -16.f), 16.f);
    float e = __builtin_amdgcn_exp2f(t * 2.885390082f);   // exp(2t)
    return 1.f - 2.f * __builtin_amdgcn_rcpf(e + 1.f);
}

// async global->LDS 16B copy (gfx950). LDS dest rule: wave-uniform base +
// lane*16 -- our per-lane laddr matches that rule exactly (linear).
__device__ __forceinline__ void gload_lds16(const void* g, void* l) {
    __builtin_amdgcn_global_load_lds(
        (const __attribute__((address_space(1))) unsigned*)g,
        (__attribute__((address_space(3))) unsigned*)l, 16, 0, 0);
}

// ---------------------------------------------------------------------------
// f32 -> f16 convert pass (memory-bound). Same rounding as the old
// in-staging convert => bit-identical downstream math. (r10-proven)
// ---------------------------------------------------------------------------
__global__ __launch_bounds__(256) void cvt_f16(const float4* __restrict__ src,
                                               half4v* __restrict__ dst, int n4) {
    int i = blockIdx.x * blockDim.x + threadIdx.x;
    const int stride = gridDim.x * blockDim.x;
    for (; i < n4; i += stride) {
        const float4 v = src[i];
        half4v h = { (_Float16)v.x, (_Float16)v.y, (_Float16)v.z, (_Float16)v.w };
        dst[i] = h;
    }
}

// ---------------------------------------------------------------------------
// Phase 1 (fast path): f16 GEMM with global_load_lds staging (r12).
// 128x128 / BK=64 / XCD-swizzled structure (r10/r11-proven geometry).
// Staging: 8 async gload_lds16 per thread per K-iter -- no VGPR round trip,
// no LDS store instructions (was: 8 b128 loads + 8 b128 stores).
// LDS [128][64] f16 (linear, stride 128B) + XOR chunk swizzle:
//   store: lane l fetches chunk c=(l&7)^((l>>3)&7) of its row -> linear dest
//   read:  slot = (sub*4+q) ^ (row&7)
// (source permutation == read permutation; both-sides rule #21. Bank spread
// equals the proven stride-72 layout: 2-way residual = free.)
// ---------------------------------------------------------------------------
__global__ __launch_bounds__(256) void gemm_xp_f16(const _Float16* __restrict__ xh,
                                                   const _Float16* __restrict__ Wh,
                                                   const float* __restrict__ bih,
                                                   float* __restrict__ out) {
    __shared__ alignas(16) _Float16 As[128 * 64];   // 16KB, linear
    __shared__ alignas(16) _Float16 Bs[128 * 64];

    const int tid  = threadIdx.x;
    const int xcd  = blockIdx.x & 7;               // same-bm blocks share an XCD
    const int idx  = blockIdx.x >> 3;
    const int bm   = xcd + 8 * (idx >> 3);
    const int bn   = idx & 7;
    const int M0   = bm * 128, N0 = bn * 128;
    const int lane = tid & 63, w = tid >> 6;
    const int wm   = (w & 1) * 64, wn = (w >> 1) * 64;
    const int ro   = lane & 15, q = lane >> 4;

    // staging geometry: pass ir stages rows ir*32 + w*8 + (lane>>3),
    // chunk c = (lane&7) ^ ((lane>>3)&7)  [row&7 == (lane>>3)&7].
    const int srow  = w * 8 + (lane >> 3);         // row within 32-row pass
    const int schunk = (lane & 7) ^ ((lane >> 3) & 7);
    _Float16* ldsA = As + (size_t)(w * 8) * 64 + (size_t)(lane & 63) * 0 + (size_t)((lane >> 3)) * 64 + (lane & 7) * 8;
    // NOTE: ldsA above == As + srow*64 + (lane&7)*8 == linear lane*8 within
    // the wave's 1024-elem window -- matches the lane*16B dest rule.
    _Float16* ldsB = Bs + (size_t)srow * 64 + (lane & 7) * 8;
    ldsA = As + (size_t)srow * 64 + (lane & 7) * 8;

    const f32x4 zero4 = {0.f, 0.f, 0.f, 0.f};
    f32x4 acc[4][4];
    #pragma unroll
    for (int i = 0; i < 4; ++i)
        #pragma unroll
        for (int j = 0; j < 4; ++j) acc[i][j] = zero4;

    for (int kk = 0; kk < 16; ++kk) {              // BK=64
        const int k0 = kk * 64;
        #pragma unroll
        for (int ir = 0; ir < 4; ++ir) {
            const int row = ir * 32 + srow;
            gload_lds16(xh + (size_t)(M0 + row) * II_ + k0 + schunk * 8,
                        ldsA + ir * 32 * 64);
            gload_lds16(Wh + (size_t)(N0 + row) * II_ + k0 + schunk * 8,
                        ldsB + ir * 32 * 64);
        }
        __syncthreads();   // drains vmcnt (incl. global_load_lds) + joins WG

        half8 a[2][4], b[2][4];
        #pragma unroll
        for (int sub = 0; sub < 2; ++sub)
            #pragma unroll
            for (int i = 0; i < 4; ++i) {
                const int Ra = wm + i * 16 + ro;
                const int Rb = wn + i * 16 + ro;
                a[sub][i] = *(const half8*)(As + Ra * 64 + (((sub * 4 + q) ^ (Ra & 7)) * 8));
                b[sub][i] = *(const half8*)(Bs + Rb * 64 + (((sub * 4 + q) ^ (Rb & 7)) * 8));
            }
        #pragma unroll
        for (int sub = 0; sub < 2; ++sub)
            #pragma unroll
            for (int i = 0; i < 4; ++i)
                #pragma unroll
                for (int j = 0; j < 4; ++j)
                    acc[i][j] = __builtin_amdgcn_mfma_f32_16x16x32_f16(a[sub][i], b[sub][j], acc[i][j], 0, 0, 0);
        __syncthreads();
    }

    #pragma unroll
    for (int j = 0; j < 4; ++j) {
        const int col = N0 + wn + j * 16 + ro;
        const float bias = bih[col];
        #pragma unroll
        for (int i = 0; i < 4; ++i) {
            #pragma unroll
            for (int r = 0; r < 4; ++r) {
                const int rowg = M0 + wm + i * 16 + q * 4 + r;
                out[(size_t)rowg * HH_ + col] = acc[i][j][r] + bias;
            }
        }
    }
}

// ---------------------------------------------------------------------------
// Phase 1 (fallback, ws too small): r9 gemm verbatim.
// ---------------------------------------------------------------------------
__global__ __launch_bounds__(256) void gemm_xp(const float* __restrict__ x,
                                               const float* __restrict__ Wih,
                                               const float* __restrict__ bih,
                                               float* __restrict__ out) {
    __shared__ alignas(16) _Float16 As[2][128 * 40];
    __shared__ alignas(16) _Float16 Bs[2][128 * 40];

    const int tid  = threadIdx.x;
    const int xcd  = blockIdx.x & 7;
    const int idx  = blockIdx.x >> 3;
    const int bm   = xcd + 8 * (idx >> 3);
    const int bn   = idx & 7;
    const int M0   = bm * 128, N0 = bn * 128;
    const int lane = tid & 63, w = tid >> 6;
    const int wm   = (w & 1) * 64, wn = (w >> 1) * 64;
    const int ro   = lane & 15, q = lane >> 4;
    const int sr   = tid >> 3, sc = tid & 7;

    const f32x4 zero4 = {0.f, 0.f, 0.f, 0.f};
    f32x4 acc[4][4];
    #pragma unroll
    for (int i = 0; i < 4; ++i)
        #pragma unroll
        for (int j = 0; j < 4; ++j) acc[i][j] = zero4;

    for (int kk = 0; kk < 16; ++kk) {
        #pragma unroll
        for (int sub = 0; sub < 2; ++sub) {
            const int k0 = kk * 64 + sub * 32;
            #pragma unroll
            for (int ir = 0; ir < 4; ++ir) {
                const int row = ir * 32 + sr;
                const float4 av = *(const float4*)(x   + (size_t)(M0 + row) * II_ + k0 + sc * 4);
                const float4 bv = *(const float4*)(Wih + (size_t)(N0 + row) * II_ + k0 + sc * 4);
                half4v ah = { (_Float16)av.x, (_Float16)av.y, (_Float16)av.z, (_Float16)av.w };
                half4v bh = { (_Float16)bv.x, (_Float16)bv.y, (_Float16)bv.z, (_Float16)bv.w };
                *(half4v*)(As[sub] + row * 40 + sc * 4) = ah;
                *(half4v*)(Bs[sub] + row * 40 + sc * 4) = bh;
            }
        }
        __syncthreads();

        half8 a[2][4], b[2][4];
        #pragma unroll
        for (int sub = 0; sub < 2; ++sub)
            #pragma unroll
            for (int i = 0; i < 4; ++i) {
                a[sub][i] = *(const half8*)(As[sub] + (wm + i * 16 + ro) * 40 + q * 8);
                b[sub][i] = *(const half8*)(Bs[sub] + (wn + i * 16 + ro) * 40 + q * 8);
            }
        #pragma unroll
        for (int sub = 0; sub < 2; ++sub)
            #pragma unroll
            for (int i = 0; i < 4; ++i)
                #pragma unroll
                for (int j = 0; j < 4; ++j)
                    acc[i][j] = __builtin_amdgcn_mfma_f32_16x16x32_f16(a[sub][i], b[sub][j], acc[i][j], 0, 0, 0);
        __syncthreads();
    }

    #pragma unroll
    for (int j = 0; j < 4; ++j) {
        const int col = N0 + wn + j * 16 + ro;
        const float bias = bih[col];
        #pragma unroll
        for (int i = 0; i < 4; ++i) {
            #pragma unroll
            for (int r = 0; r < 4; ++r) {
                const int rowg = M0 + wm + i * 16 + q * 4 + r;
                out[(size_t)rowg * HH_ + col] = acc[i][j][r] + bias;
            }
        }
    }
}

// ---------------------------------------------------------------------------
// Phase 2: persistent recurrence -- r9/r11 VERBATIM (best: ~1128us, three
// green runs). Simple single-round poll + 3-op XOR tag check. Retired by
// experiment: sc0 store (r2/r4 hang), sc0 poll (r3 +120us), fat-WG (r5),
// degree-8 (r7), fusion (r8), pipelined poll (r10) -- every addition to the
// poll loop or serial chain costs ~1.2x its cycles in step period.
// ---------------------------------------------------------------------------
__global__ __launch_bounds__(256, 1) void rnn_steps(const float* __restrict__ Whh,
                                                    const float* __restrict__ bhh,
                                                    const float* __restrict__ h0,
                                                    float* __restrict__ out,
                                                    unsigned* __restrict__ comm) {
    __shared__ alignas(16) _Float16 hbuf[2][5][1032];

    const int tid  = threadIdx.x;
    const int lane = tid & 63;
    const int w    = tid >> 6;             // wave id: stages batch w, owns 16 cols
    const int g    = blockIdx.x >> 4;      // group 0..15
    const int wg   = blockIdx.x & 15;      // wg within group
    const int b0   = g * 4;
    const int j0   = wg * 64;
    const int ro   = lane & 15, q = lane >> 4;
    const int arow = (ro < 4) ? ro : 4;    // A rows >=4 read the shared zero row
    const int bat  = lane >> 4;            // epilogue: this lane's batch 0..3
    const int colw = j0 + w * 16 + (lane & 15);  // epilogue: this lane's column

    half8 wf[4][8];
    {
        const float* wrow = Whh + (size_t)(j0 + w * 16 + ro) * HH_;
        #pragma unroll
        for (int kq = 0; kq < 4; ++kq) {
            #pragma unroll
            for (int ks = 0; ks < 8; ++ks) {
                const int kc = kq * 256 + ks * 32 + q * 8;
                const float4 w0 = *(const float4*)(wrow + kc);
                const float4 w1 = *(const float4*)(wrow + kc + 4);
                half8 hv;
                hv[0] = (_Float16)w0.x; hv[1] = (_Float16)w0.y;
                hv[2] = (_Float16)w0.z; hv[3] = (_Float16)w0.w;
                hv[4] = (_Float16)w1.x; hv[5] = (_Float16)w1.y;
                hv[6] = (_Float16)w1.z; hv[7] = (_Float16)w1.w;
                wf[kq][ks] = hv;
            }
        }
    }
    const float bhh_r = bhh[colw];

    for (int i = tid; i < 1032; i += 256) {
        hbuf[0][4][i] = (_Float16)0.f;
        hbuf[1][4][i] = (_Float16)0.f;
    }

    const f32x4 zero4 = {0.f, 0.f, 0.f, 0.f};

    #define TAGMSK_ 0xFFFF0000FFFF0000ull
    #define TAGOK_(v) ((((v) ^ pat) & TAGMSK_) == 0)

    for (int s = 0; s < TT_; ++s) {
        const int slot = s & 1;

        const float xpv = out[((size_t)(b0 + bat) * TT_ + s) * HH_ + colw];

        unsigned* dstw = (unsigned*)(&hbuf[slot][w][0]);
        if (s == 0) {
            const float2* hrow = (const float2*)(h0 + (size_t)(b0 + w) * HH_);
            #pragma unroll
            for (int c = 0; c < 8; ++c) {
                const float2 hv = hrow[c * 64 + lane];
                union { _Float16 h[2]; unsigned u; } pk;
                pk.h[0] = (_Float16)hv.x; pk.h[1] = (_Float16)hv.y;
                dstw[c * 64 + lane] = pk.u;
            }
        } else {
            const unsigned long long pat =
                ((unsigned long long)(unsigned)s << 48) |
                ((unsigned long long)(unsigned)s << 16);
            const unsigned long long* sp = (const unsigned long long*)
                (comm + (size_t)slot * (BB_ * HH_) + (size_t)(b0 + w) * HH_);
            unsigned long long v0, v1, v2, v3, v4, v5, v6, v7;
            bool ok = false;
            while (!ok) {
                v0 = __hip_atomic_load(sp + 0 * 64 + lane, __ATOMIC_RELAXED, __HIP_MEMORY_SCOPE_AGENT);
                v1 = __hip_atomic_load(sp + 1 * 64 + lane, __ATOMIC_RELAXED, __HIP_MEMORY_SCOPE_AGENT);
                v2 = __hip_atomic_load(sp + 2 * 64 + lane, __ATOMIC_RELAXED, __HIP_MEMORY_SCOPE_AGENT);
                v3 = __hip_atomic_load(sp + 3 * 64 + lane, __ATOMIC_RELAXED, __HIP_MEMORY_SCOPE_AGENT);
                v4 = __hip_atomic_load(sp + 4 * 64 + lane, __ATOMIC_RELAXED, __HIP_MEMORY_SCOPE_AGENT);
                v5 = __hip_atomic_load(sp + 5 * 64 + lane, __ATOMIC_RELAXED, __HIP_MEMORY_SCOPE_AGENT);
                v6 = __hip_atomic_load(sp + 6 * 64 + lane, __ATOMIC_RELAXED, __HIP_MEMORY_SCOPE_AGENT);
                v7 = __hip_atomic_load(sp + 7 * 64 + lane, __ATOMIC_RELAXED, __HIP_MEMORY_SCOPE_AGENT);
                bool o = true;
                o &= TAGOK_(v0); o &= TAGOK_(v1); o &= TAGOK_(v2); o &= TAGOK_(v3);
                o &= TAGOK_(v4); o &= TAGOK_(v5); o &= TAGOK_(v6); o &= TAGOK_(v7);
                ok = o;
            }
            #define PACK_(x) ((unsigned)((x) & 0xffffull) | (((unsigned)((x) >> 32)) << 16))
            dstw[0 * 64 + lane] = PACK_(v0);
            dstw[1 * 64 + lane] = PACK_(v1);
            dstw[2 * 64 + lane] = PACK_(v2);
            dstw[3 * 64 + lane] = PACK_(v3);
            dstw[4 * 64 + lane] = PACK_(v4);
            dstw[5 * 64 + lane] = PACK_(v5);
            dstw[6 * 64 + lane] = PACK_(v6);
            dstw[7 * 64 + lane] = PACK_(v7);
            #undef PACK_
        }
        __syncthreads();   // the only barrier per step (LDS double-buffered)

        f32x4 acc[4] = {zero4, zero4, zero4, zero4};
        const _Float16* abase = &hbuf[slot][0][0] + (size_t)arow * 1032;
        #pragma unroll
        for (int kq = 0; kq < 4; ++kq) {
            #pragma unroll
            for (int ks = 0; ks < 8; ++ks) {
                const half8 a = *(const half8*)(abase + kq * 256 + ks * 32 + q * 8);
                acc[kq] = __builtin_amdgcn_mfma_f32_16x16x32_f16(a, wf[kq][ks], acc[kq], 0, 0, 0);
            }
        }

        const f32x4 sum = acc[0] + acc[1] + acc[2] + acc[3];
        const float t0 = __shfl(sum[0], lane & 15);
        const float t1 = __shfl(sum[1], lane & 15);
        const float t2 = __shfl(sum[2], lane & 15);
        const float t3 = __shfl(sum[3], lane & 15);
        const float val = (bat == 0) ? t0 : (bat == 1) ? t1 : (bat == 2) ? t2 : t3;

        const float hnew = fast_tanh(xpv + bhh_r + val);

        union { _Float16 h; unsigned short us; } cv; cv.h = (_Float16)hnew;
        const unsigned word = ((unsigned)(s + 1) << 16) | (unsigned)cv.us;
        __hip_atomic_store(comm + (size_t)((s + 1) & 1) * (BB_ * HH_)
                                + (size_t)(b0 + bat) * HH_ + colw,
                           word, __ATOMIC_RELAXED, __HIP_MEMORY_SCOPE_AGENT);

        out[((size_t)(b0 + bat) * TT_ + s) * HH_ + colw] = hnew;
    }
    #undef TAGOK_
    #undef TAGMSK_
}

// ---------------------------------------------------------------------------
extern "C" void kernel_launch(void* const* d_in, const int* in_sizes, int n_in,
                              void* d_out, int out_size, void* d_ws, size_t ws_size,
                              hipStream_t stream) {
    (void)in_sizes; (void)n_in; (void)out_size;

    const float* x   = (const float*)d_in[0];
    const float* h0  = (const float*)d_in[1];
    const float* Wih = (const float*)d_in[2];
    const float* bih = (const float*)d_in[3];
    const float* Whh = (const float*)d_in[4];
    const float* bhh = (const float*)d_in[5];
    float* out = (float*)d_out;

    // ws layout: comm (512KB, r1-proven offsets) | Wih_f16 (2MB) | x_f16 (64MB)
    const size_t COMMB = 2 * (size_t)(BB_ * HH_) * sizeof(unsigned);
    const size_t WFB   = (size_t)HH_ * II_ * sizeof(_Float16);
    const size_t XFB   = (size_t)BB_ * TT_ * II_ * sizeof(_Float16);
    unsigned* comm = (unsigned*)d_ws;

    if (ws_size >= COMMB + WFB + XFB) {
        _Float16* Wh = (_Float16*)((char*)d_ws + COMMB);
        _Float16* xh = (_Float16*)((char*)d_ws + COMMB + WFB);
        cvt_f16<<<512, 256, 0, stream>>>((const float4*)Wih, (half4v*)Wh,
                                         HH_ * II_ / 4);
        cvt_f16<<<2048, 256, 0, stream>>>((const float4*)x, (half4v*)xh,
                                          BB_ * TT_ * II_ / 4);
        gemm_xp_f16<<<2048, 256, 0, stream>>>(xh, Wh, bih, out);
    } else {
        gemm_xp<<<2048, 256, 0, stream>>>(x, Wih, bih, out);
    }
    rnn_steps<<<256, 256, 0, stream>>>(Whh, bhh, h0, out, comm);
}